// Round 1
// baseline (3325.682 us; speedup 1.0000x reference)
//
#include <hip/hip_runtime.h>
#include <hip/hip_bf16.h>

// CharRNN via closed-form affine scan:
//   h_{t+1} = h_t @ P + c_t,  P = I + 0.01*W_eff^T (time-invariant)
//   h_1024  = Horner over 32 chunks of 32 steps, with W_in folded into the
//             power stack Q_k = W_in^T @ P^k  ->  one big fp16 MFMA GEMM.
// Identity is kept OUT of every MFMA (X@P = X + X@R), state carried in f32,
// R stored *64 to stay clear of fp16 denormals.

typedef _Float16 half8  __attribute__((ext_vector_type(8)));
typedef _Float16 half4h __attribute__((ext_vector_type(4)));
typedef float    f32x4  __attribute__((ext_vector_type(4)));

#define SEQ_    1024
#define BATCH_  128
#define HID_    2048
#define EMB_    512
#define VOC_    50257

__device__ __forceinline__ float decode_temp(const void* tp) {
  // temperature arrives as a 1-element array; dtype (int vs float) unknown.
  int bits = *(const int*)tp;
  float f = __int_as_float(bits);
  if (!(f > 1e-6f && f < 1e6f)) f = (float)bits;
  return f;
}

// ---------------------------------------------------------------- small preps
__global__ void cast_f2h_k(const float* __restrict__ src, _Float16* __restrict__ dst, int n8) {
  int t = blockIdx.x * 256 + threadIdx.x;
  if (t >= n8) return;
  const f32x4 a = *(const f32x4*)(src + (size_t)t * 8);
  const f32x4 b = *(const f32x4*)(src + (size_t)t * 8 + 4);
  half8 h = { (_Float16)a[0], (_Float16)a[1], (_Float16)a[2], (_Float16)a[3],
              (_Float16)b[0], (_Float16)b[1], (_Float16)b[2], (_Float16)b[3] };
  *(half8*)(dst + (size_t)t * 8) = h;
}

// Rt[i][j] = 64*0.01*W_eff^T[i][j]; also write fp16 and fp16-transposed copies.
__global__ void prep_R_k(const float* __restrict__ Wh, float* __restrict__ R32,
                         _Float16* __restrict__ R16, _Float16* __restrict__ RT16) {
  const int idx = blockIdx.x * 256 + threadIdx.x;
  const int i = idx >> 11, j = idx & 2047;
  float v = 0.64f * (Wh[(size_t)j * HID_ + i] - Wh[(size_t)i * HID_ + j]);
  if (i == j) v = -6.4e-4f;                    // -64*0.01*DIFFUSION
  R32[idx] = v;
  R16[idx] = (_Float16)v;
  RT16[idx] = (_Float16)((i == j) ? v : -v);   // R is antisymmetric off-diagonal
}

// QT[n][31*512 + e] = W_in[n][e]   (the k=0 power slot of the transposed stack)
__global__ void copy_win_qt_k(const float* __restrict__ Win, _Float16* __restrict__ QT) {
  int t = blockIdx.x * 256 + threadIdx.x;           // HID_*EMB_/4 threads
  int n = t / (EMB_ / 4), c4 = (t % (EMB_ / 4)) * 4;
  const f32x4 v = *(const f32x4*)(Win + (size_t)n * EMB_ + c4);
  half4h h = { (_Float16)v[0], (_Float16)v[1], (_Float16)v[2], (_Float16)v[3] };
  *(half4h*)(QT + (size_t)n * 16384 + 31 * EMB_ + c4) = h;
}

// generic f32 -> fp16 transpose (64x64 tiles). dst[(x)][y] = src[y][x]
__global__ void transpose_f2h_k(const float* __restrict__ src, int ldsrc,
                                _Float16* __restrict__ dst, int lddst) {
  __shared__ float t[64][68];
  const int x0 = blockIdx.x * 64, y0 = blockIdx.y * 64;
  const int tid = threadIdx.x;
  const int xc = (tid & 15) * 4, ry = tid >> 4;
#pragma unroll
  for (int p = 0; p < 4; ++p) {
    int row = ry + p * 16;
    const f32x4 v = *(const f32x4*)(src + (size_t)(y0 + row) * ldsrc + x0 + xc);
    *(f32x4*)&t[row][xc] = v;
  }
  __syncthreads();
#pragma unroll
  for (int p = 0; p < 4; ++p) {
    int r2 = ry + p * 16;
    half4h h = { (_Float16)t[xc][r2], (_Float16)t[xc + 1][r2],
                 (_Float16)t[xc + 2][r2], (_Float16)t[xc + 3][r2] };
    *(half4h*)(dst + (size_t)(x0 + r2) * lddst + y0 + xc) = h;
  }
}

// transpose fresh Q slots into the K-major stack: QT[n][(31-slot)*512 + e] = Qslot[e][n]
__global__ void transpose_q_k(const _Float16* __restrict__ Qst, int firstslot,
                              _Float16* __restrict__ QT) {
  __shared__ _Float16 t[64][72];
  const int slot = firstslot + blockIdx.z;
  const _Float16* src = Qst + (size_t)slot * (EMB_ * HID_);
  const int dc0 = (31 - slot) * EMB_;
  const int x0 = blockIdx.x * 64, y0 = blockIdx.y * 64;  // x: n (2048), y: e (512)
  const int tid = threadIdx.x;
  const int xc = (tid & 7) * 8, ry = tid >> 3;
#pragma unroll
  for (int p = 0; p < 2; ++p) {
    int row = ry + p * 32;
    *(half8*)&t[row][xc] = *(const half8*)(src + (size_t)(y0 + row) * HID_ + x0 + xc);
  }
  __syncthreads();
#pragma unroll
  for (int p = 0; p < 2; ++p) {
    int r2 = ry + p * 32;
    half8 h = { t[xc][r2],     t[xc + 1][r2], t[xc + 2][r2], t[xc + 3][r2],
                t[xc + 4][r2], t[xc + 5][r2], t[xc + 6][r2], t[xc + 7][r2] };
    *(half8*)(QT + (size_t)(x0 + r2) * 16384 + dc0 + y0 + xc) = h;
  }
}

// g_{2m} = 2 g_m + (g_m @ Rt_m)/64  (vector-matrix, coalesced over columns)
__global__ void gvec_k(const float* __restrict__ gin, const float* __restrict__ R32,
                       float* __restrict__ gout) {
  const int j = blockIdx.x * blockDim.x + threadIdx.x;
  float acc = 0.f;
  for (int i = 0; i < HID_; ++i) acc += gin[i] * R32[(size_t)i * HID_ + j];
  gout[j] = 2.0f * gin[j] + acc * (1.0f / 64.0f);
}

// ---------------------------------------------------------------- MFMA GEMM
// C(MxN) = A(MxK) @ Bt(NxK)^T with fp16 MFMA 16x16x32, f32 accumulate.
// AM: 0=fp16 A, 1=f32 A (convert), 2=gather fp16 embedding rows via ids
// BMO: 0=fp16 Bt, 1=f32 Bt (convert, N-bounded)
// EPI: 0 squaring  out = acc/64 + 2*Rin          (writes f32 + fp16)
//      1 Qdouble   out16 = fp16(acc/64 + Qin16)
//      2 inner     S[z] = 0.01*(acc + beta[col])
//      3 combine   Hout = Hprev + acc/64 + Sq
//      4 logits    out = (acc + fcb[col]) / T     (N-bounded)
template<int BM, int BN, int BK, int WM, int WN, int AM, int BMO, int EPI>
__global__ __launch_bounds__(256) void gemm_k(
    const void* __restrict__ Ap, int lda,
    const void* __restrict__ Bp, int ldb,
    int K, int Ntot, int ldc,
    const int* __restrict__ ids, const _Float16* __restrict__ emb,
    float* __restrict__ o32, _Float16* __restrict__ o16,
    const float* __restrict__ aux32, const float* __restrict__ aux32b,
    const _Float16* __restrict__ aux16,
    const float* __restrict__ vecf, const void* __restrict__ tptr) {
  constexpr int PAD = 8;
  __shared__ _Float16 At[BM][BK + PAD];
  __shared__ _Float16 Bts[BN][BK + PAD];
  constexpr int MF = WM / 16, NF = WN / 16;
  constexpr int WNB = BN / WN;
  const int tid = threadIdx.x;
  const int lane = tid & 63, w = tid >> 6;
  const int wm0 = (w / WNB) * WM, wn0 = (w % WNB) * WN;
  const int bn0 = blockIdx.x * BN, bm0 = blockIdx.y * BM;

  f32x4 acc[MF][NF];
#pragma unroll
  for (int mf = 0; mf < MF; ++mf)
#pragma unroll
    for (int nf = 0; nf < NF; ++nf) acc[mf][nf] = (f32x4){0.f, 0.f, 0.f, 0.f};

  for (int k0 = 0; k0 < K; k0 += BK) {
    // ---- stage A tile
    if constexpr (AM == 0) {
      const _Float16* Ag = (const _Float16*)Ap;
      constexpr int CH = BK / 8;
#pragma unroll
      for (int c = 0; c < (BM * CH) / 256; ++c) {
        int t = tid + c * 256;
        int row = t / CH, kc = t % CH;
        *(half8*)&At[row][kc * 8] =
            *(const half8*)(Ag + (size_t)(bm0 + row) * lda + k0 + kc * 8);
      }
    } else if constexpr (AM == 1) {
      const float* Ag = (const float*)Ap;
      constexpr int CH = BK / 4;
#pragma unroll
      for (int c = 0; c < (BM * CH) / 256; ++c) {
        int t = tid + c * 256;
        int row = t / CH, kc = t % CH;
        f32x4 v = *(const f32x4*)(Ag + (size_t)(bm0 + row) * lda + k0 + kc * 4);
        half4h h = { (_Float16)v[0], (_Float16)v[1], (_Float16)v[2], (_Float16)v[3] };
        *(half4h*)&At[row][kc * 4] = h;
      }
    } else {  // AM==2: gather embedding rows, chunk = blockIdx.z, T=32, E=512
      constexpr int CH = BK / 8;
      const int r = k0 >> 9, e0 = k0 & 511;
      const int* idrow = ids + (size_t)(blockIdx.z * 32 + r) * BATCH_;
#pragma unroll
      for (int c = 0; c < (BM * CH) / 256; ++c) {
        int t = tid + c * 256;
        int row = t / CH, kc = t % CH;
        int id = idrow[row];
        *(half8*)&At[row][kc * 8] =
            *(const half8*)(emb + (size_t)id * EMB_ + e0 + kc * 8);
      }
    }
    // ---- stage Bt tile
    if constexpr (BMO == 0) {
      const _Float16* Bg = (const _Float16*)Bp;
      constexpr int CH = BK / 8;
#pragma unroll
      for (int c = 0; c < (BN * CH) / 256; ++c) {
        int t = tid + c * 256;
        int row = t / CH, kc = t % CH;
        *(half8*)&Bts[row][kc * 8] =
            *(const half8*)(Bg + (size_t)(bn0 + row) * ldb + k0 + kc * 8);
      }
    } else {
      const float* Bg = (const float*)Bp;
      constexpr int CH = BK / 4;
#pragma unroll
      for (int c = 0; c < (BN * CH) / 256; ++c) {
        int t = tid + c * 256;
        int row = t / CH, kc = t % CH;
        int gr = bn0 + row;
        half4h h = { (_Float16)0.f, (_Float16)0.f, (_Float16)0.f, (_Float16)0.f };
        if (gr < Ntot) {
          f32x4 v = *(const f32x4*)(Bg + (size_t)gr * ldb + k0 + kc * 4);
          h = (half4h){ (_Float16)v[0], (_Float16)v[1], (_Float16)v[2], (_Float16)v[3] };
        }
        *(half4h*)&Bts[row][kc * 4] = h;
      }
    }
    __syncthreads();
#pragma unroll
    for (int kk = 0; kk < BK; kk += 32) {
      const int kb = kk + ((lane >> 4) << 3);
      half8 a[MF], b[NF];
#pragma unroll
      for (int mf = 0; mf < MF; ++mf)
        a[mf] = *(const half8*)&At[wm0 + mf * 16 + (lane & 15)][kb];
#pragma unroll
      for (int nf = 0; nf < NF; ++nf)
        b[nf] = *(const half8*)&Bts[wn0 + nf * 16 + (lane & 15)][kb];
#pragma unroll
      for (int mf = 0; mf < MF; ++mf)
#pragma unroll
        for (int nf = 0; nf < NF; ++nf)
          acc[mf][nf] = __builtin_amdgcn_mfma_f32_16x16x32_f16(a[mf], b[nf], acc[mf][nf], 0, 0, 0);
    }
    __syncthreads();
  }

  // ---- epilogue; C/D layout: col = lane&15, row = (lane>>4)*4 + reg
  float invT = 1.0f;
  if constexpr (EPI == 4) invT = 1.0f / decode_temp(tptr);
#pragma unroll
  for (int mf = 0; mf < MF; ++mf)
#pragma unroll
    for (int nf = 0; nf < NF; ++nf) {
      const int col = bn0 + wn0 + nf * 16 + (lane & 15);
      const int row0 = bm0 + wm0 + mf * 16 + ((lane >> 4) << 2);
#pragma unroll
      for (int r = 0; r < 4; ++r) {
        const int row = row0 + r;
        const float x = acc[mf][nf][r];
        const size_t idx = (size_t)row * ldc + col;
        if constexpr (EPI == 0) {
          float val = x * (1.0f / 64.0f) + 2.0f * aux32[idx];
          o32[idx] = val;
          o16[idx] = (_Float16)val;
        } else if constexpr (EPI == 1) {
          o16[idx] = (_Float16)(x * (1.0f / 64.0f) + (float)aux16[idx]);
        } else if constexpr (EPI == 2) {
          o32[(size_t)blockIdx.z * (BATCH_ * HID_) + idx] = 0.01f * (x + vecf[col]);
        } else if constexpr (EPI == 3) {
          o32[idx] = aux32[idx] + x * (1.0f / 64.0f) + aux32b[idx];
        } else {
          if (col < Ntot) o32[idx] = (x + vecf[col]) * invT;
        }
      }
    }
}

// ---------------------------------------------------------------- softmax rows
__global__ void softmax_k(const float* __restrict__ lg, float* __restrict__ out) {
  const int row = blockIdx.x;
  const float* lr = lg + (size_t)row * VOC_;
  float* orow = out + (size_t)row * VOC_;
  __shared__ float red[8];
  const int tid = threadIdx.x, lane = tid & 63, wid = tid >> 6;
  float m = -1e30f;
  for (int i = tid; i < VOC_; i += 256) m = fmaxf(m, lr[i]);
  for (int off = 32; off > 0; off >>= 1) m = fmaxf(m, __shfl_down(m, off, 64));
  if (lane == 0) red[wid] = m;
  __syncthreads();
  if (tid == 0) {
    float mm = red[0];
    for (int i = 1; i < 4; ++i) mm = fmaxf(mm, red[i]);
    red[4] = mm;
  }
  __syncthreads();
  const float bmax = red[4];
  float s = 0.f;
  for (int i = tid; i < VOC_; i += 256) s += __expf(lr[i] - bmax);
  for (int off = 32; off > 0; off >>= 1) s += __shfl_down(s, off, 64);
  if (lane == 0) red[wid] = s;
  __syncthreads();
  if (tid == 0) red[5] = red[0] + red[1] + red[2] + red[3];
  __syncthreads();
  const float inv = 1.0f / red[5];
  for (int i = tid; i < VOC_; i += 256) orow[i] = __expf(lr[i] - bmax) * inv;
}

// ---------------------------------------------------------------- launcher
extern "C" void kernel_launch(void* const* d_in, const int* in_sizes, int n_in,
                              void* d_out, int out_size, void* d_ws, size_t ws_size,
                              hipStream_t stream) {
  const int*   ids  = (const int*)d_in[0];
  const float* h0   = (const float*)d_in[1];
  const float* embf = (const float*)d_in[2];
  const float* Win  = (const float*)d_in[3];
  const float* Wh   = (const float*)d_in[4];
  const float* bias = (const float*)d_in[5];
  const float* fcw  = (const float*)d_in[6];
  const float* fcb  = (const float*)d_in[7];
  const void*  temp = d_in[8];
  float* out = (float*)d_out;

  char* w = (char*)d_ws;
  _Float16* emb16 = (_Float16*)w;
  float* logits = (float*)w;  // alias: emb16 dead before logits written
  size_t o = (size_t)VOC_ * EMB_ * 2;
  float* R32[2]; _Float16* R16[2]; _Float16* RT16[2];
  for (int s = 0; s < 2; ++s) {
    R32[s] = (float*)(w + o);     o += (size_t)HID_ * HID_ * 4;
    R16[s] = (_Float16*)(w + o);  o += (size_t)HID_ * HID_ * 2;
    RT16[s] = (_Float16*)(w + o); o += (size_t)HID_ * HID_ * 2;
  }
  _Float16* Qst = (_Float16*)(w + o); o += (size_t)32 * EMB_ * HID_ * 2;
  _Float16* QT  = (_Float16*)(w + o); o += (size_t)HID_ * 16384 * 2;
  float* S = (float*)(w + o);         o += (size_t)32 * BATCH_ * HID_ * 4;
  float* Hb[2];
  Hb[0] = (float*)(w + o); o += (size_t)BATCH_ * HID_ * 4;
  Hb[1] = (float*)(w + o); o += (size_t)BATCH_ * HID_ * 4;
  float* g[2];
  g[0] = (float*)(w + o); o += 8192;
  g[1] = (float*)(w + o); o += 8192;
  if (ws_size < o) return;  // needs ~289 MB scratch

  const size_t QSLOT = (size_t)EMB_ * HID_;

  cast_f2h_k<<<(VOC_ * EMB_ / 8 + 255) / 256, 256, 0, stream>>>(embf, emb16, VOC_ * EMB_ / 8);
  prep_R_k<<<HID_ * HID_ / 256, 256, 0, stream>>>(Wh, R32[0], R16[0], RT16[0]);
  transpose_f2h_k<<<dim3(EMB_ / 64, HID_ / 64), 256, 0, stream>>>(Win, EMB_, Qst, HID_);
  copy_win_qt_k<<<(HID_ * EMB_ / 4) / 256, 256, 0, stream>>>(Win, QT);

  for (int j = 0; j < 5; ++j) {
    const int sl = j & 1;
    const int nb = 1 << j;
    // Q doubling: slots [nb,2nb) = slots [0,nb) @ P^(2^j)
    gemm_k<128, 128, 64, 64, 64, 0, 0, 1>
        <<<dim3(HID_ / 128, (EMB_ * nb) / 128), 256, 0, stream>>>(
        Qst, HID_, RT16[sl], HID_, HID_, HID_, HID_, nullptr, nullptr,
        nullptr, Qst + (size_t)nb * QSLOT, nullptr, nullptr, Qst, nullptr, nullptr);
    transpose_q_k<<<dim3(HID_ / 64, EMB_ / 64, nb), 256, 0, stream>>>(Qst, nb, QT);
    gvec_k<<<HID_ / 256, 256, 0, stream>>>(j == 0 ? bias : g[(j + 1) & 1], R32[sl], g[j & 1]);
    // squaring: R_{2m} = 2 R_m + R_m^2
    gemm_k<128, 128, 64, 64, 64, 0, 0, 0>
        <<<dim3(HID_ / 128, HID_ / 128), 256, 0, stream>>>(
        R16[sl], HID_, RT16[sl], HID_, HID_, HID_, HID_, nullptr, nullptr,
        R32[sl ^ 1], R16[sl ^ 1], R32[sl], nullptr, nullptr, nullptr, nullptr);
    transpose_f2h_k<<<dim3(HID_ / 64, HID_ / 64), 256, 0, stream>>>(R32[sl ^ 1], HID_, RT16[sl ^ 1], HID_);
  }

  // inner fused GEMM: S_q = 0.01*( X_q @ Qstack + beta ), K = 32*512
  gemm_k<128, 128, 64, 64, 64, 2, 0, 2>
      <<<dim3(HID_ / 128, 1, 32), 256, 0, stream>>>(
      nullptr, 0, QT, 16384, 16384, HID_, HID_, ids, emb16,
      S, nullptr, nullptr, nullptr, nullptr, g[0], nullptr);

  // Horner combine: H <- H + (H @ Rt32)/64 + S_q   (32 steps, P^32 per step)
  for (int q = 0; q < 32; ++q) {
    const float* hin = (q == 0) ? h0 : Hb[(q + 1) & 1];
    float* hout = Hb[q & 1];
    gemm_k<128, 64, 64, 64, 32, 1, 0, 3>
        <<<dim3(HID_ / 64, 1), 256, 0, stream>>>(
        hin, HID_, RT16[1], HID_, HID_, HID_, HID_, nullptr, nullptr,
        hout, nullptr, hin, S + (size_t)q * BATCH_ * HID_, nullptr, nullptr, nullptr);
  }

  // logits = (H @ fc_w^T + fc_b)/T
  gemm_k<128, 128, 64, 64, 64, 1, 1, 4>
      <<<dim3((VOC_ + 127) / 128, 1), 256, 0, stream>>>(
      Hb[1], HID_, fcw, HID_, HID_, VOC_, VOC_, nullptr, nullptr,
      logits, nullptr, nullptr, nullptr, nullptr, fcb, temp);

  softmax_k<<<BATCH_, 256, 0, stream>>>(logits, out);
}

// Round 2
// 2081.415 us; speedup vs baseline: 1.5978x; 1.5978x over previous
//
#include <hip/hip_runtime.h>
#include <hip/hip_bf16.h>

// CharRNN closed-form affine scan, round 2:
//   h_{t+1} = h_t @ P + c_t,  P = I + 0.01*W_eff^T
//   - W_in folded into 32-slot power stack -> one big fp16 MFMA GEMM
//   - combine via 5-level pair tree (P^32..P^512) instead of 32-step Horner
//   - all fp16 GEMM staging via global_load_lds(16B) with XOR chunk swizzle
//     (swizzle applied on the GLOBAL address so LDS dest stays lane-linear)
// Identity kept out of every MFMA (X@P = X + X@R); R stored *64 for fp16.

typedef _Float16 half8  __attribute__((ext_vector_type(8)));
typedef _Float16 half4h __attribute__((ext_vector_type(4)));
typedef float    f32x4  __attribute__((ext_vector_type(4)));
typedef unsigned int u32;

#define SEQ_    1024
#define BATCH_  128
#define HID_    2048
#define EMB_    512
#define VOC_    50257

__device__ __forceinline__ float decode_temp(const void* tp) {
  int bits = *(const int*)tp;
  float f = __int_as_float(bits);
  if (!(f > 1e-6f && f < 1e6f)) f = (float)bits;
  return f;
}

__device__ __forceinline__ void gl_lds16(const _Float16* g, _Float16* l) {
  __builtin_amdgcn_global_load_lds(
      (const __attribute__((address_space(1))) u32*)g,
      (__attribute__((address_space(3))) u32*)l, 16, 0, 0);
}

// ---------------------------------------------------------------- preps
// Xg2[(q*128+b)*32 + r][e] = fp16(embedding[ids[(q*32+r)*128+b]][e])
// -> rows are K-contiguous (16384) per (q,b): standard GEMM A operand.
__global__ void gather_x_k(const int* __restrict__ ids, const float* __restrict__ embf,
                           _Float16* __restrict__ Xg) {
  const int sb = blockIdx.x * 4 + (threadIdx.x >> 6);   // s*128+b
  const int lane = threadIdx.x & 63;
  const int s = sb >> 7, b = sb & 127;
  const int q = s >> 5, r = s & 31;
  const int id = ids[sb];
  const float* src = embf + (size_t)id * EMB_ + lane * 8;
  const f32x4 v0 = *(const f32x4*)src, v1 = *(const f32x4*)(src + 4);
  half8 h = { (_Float16)v0[0], (_Float16)v0[1], (_Float16)v0[2], (_Float16)v0[3],
              (_Float16)v1[0], (_Float16)v1[1], (_Float16)v1[2], (_Float16)v1[3] };
  const size_t drow = ((size_t)q * 128 + b) * 32 + r;
  *(half8*)(Xg + drow * EMB_ + lane * 8) = h;
}

// R = 64*0.01*W_eff^T, coalesced via LDS tiles. Writes R32, R16[0], RT_pow[0].
__global__ void prep_R_k(const float* __restrict__ Wh, float* __restrict__ R32,
                         _Float16* __restrict__ R16, _Float16* __restrict__ RT0) {
  __shared__ float tA[64][65], tB[64][65];
  const int bi = blockIdx.y * 64, bj = blockIdx.x * 64;
  const int tx = threadIdx.x & 63, ty = threadIdx.x >> 6;
#pragma unroll
  for (int p = 0; p < 16; ++p) {
    int r = ty + p * 4;
    tA[r][tx] = Wh[(size_t)(bi + r) * HID_ + bj + tx];
    tB[r][tx] = Wh[(size_t)(bj + r) * HID_ + bi + tx];
  }
  __syncthreads();
#pragma unroll
  for (int p = 0; p < 16; ++p) {
    int r = ty + p * 4;
    int i = bi + r, j = bj + tx;
    float v = 0.64f * (tB[tx][r] - tA[r][tx]);
    if (i == j) v = -6.4e-4f;
    size_t idx = (size_t)i * HID_ + j;
    R32[idx] = v;
    R16[idx] = (_Float16)v;
    RT0[idx] = (_Float16)((i == j) ? v : -v);
  }
}

// QT[n][31*512 + e] = W_in[n][e]   (k=0 slot of the transposed stack)
__global__ void copy_win_qt_k(const float* __restrict__ Win, _Float16* __restrict__ QT) {
  int t = blockIdx.x * 256 + threadIdx.x;
  int n = t / (EMB_ / 4), c4 = (t % (EMB_ / 4)) * 4;
  const f32x4 v = *(const f32x4*)(Win + (size_t)n * EMB_ + c4);
  half4h h = { (_Float16)v[0], (_Float16)v[1], (_Float16)v[2], (_Float16)v[3] };
  *(half4h*)(QT + (size_t)n * 16384 + 31 * EMB_ + c4) = h;
}

// generic f32 -> fp16 transpose (64x64 tiles). dst[x][y] = src[y][x]
__global__ void transpose_f2h_k(const float* __restrict__ src, int ldsrc,
                                _Float16* __restrict__ dst, int lddst) {
  __shared__ float t[64][68];
  const int x0 = blockIdx.x * 64, y0 = blockIdx.y * 64;
  const int tid = threadIdx.x;
  const int xc = (tid & 15) * 4, ry = tid >> 4;
#pragma unroll
  for (int p = 0; p < 4; ++p) {
    int row = ry + p * 16;
    const f32x4 v = *(const f32x4*)(src + (size_t)(y0 + row) * ldsrc + x0 + xc);
    *(f32x4*)&t[row][xc] = v;
  }
  __syncthreads();
#pragma unroll
  for (int p = 0; p < 4; ++p) {
    int r2 = ry + p * 16;
    half4h h = { (_Float16)t[xc][r2], (_Float16)t[xc + 1][r2],
                 (_Float16)t[xc + 2][r2], (_Float16)t[xc + 3][r2] };
    *(half4h*)(dst + (size_t)(x0 + r2) * lddst + y0 + xc) = h;
  }
}

// QT[n][(31-slot)*512 + e] = Qst[slot][e][n]
__global__ void transpose_q_k(const _Float16* __restrict__ Qst, int firstslot,
                              _Float16* __restrict__ QT) {
  __shared__ _Float16 t[64][72];
  const int slot = firstslot + blockIdx.z;
  const _Float16* src = Qst + (size_t)slot * (EMB_ * HID_);
  const int dc0 = (31 - slot) * EMB_;
  const int x0 = blockIdx.x * 64, y0 = blockIdx.y * 64;  // x: n, y: e
  const int tid = threadIdx.x;
  const int xc = (tid & 7) * 8, ry = tid >> 3;
#pragma unroll
  for (int p = 0; p < 2; ++p) {
    int row = ry + p * 32;
    *(half8*)&t[row][xc] = *(const half8*)(src + (size_t)(y0 + row) * HID_ + x0 + xc);
  }
  __syncthreads();
#pragma unroll
  for (int p = 0; p < 2; ++p) {
    int r2 = ry + p * 32;
    half8 h = { t[xc][r2],     t[xc + 1][r2], t[xc + 2][r2], t[xc + 3][r2],
                t[xc + 4][r2], t[xc + 5][r2], t[xc + 6][r2], t[xc + 7][r2] };
    *(half8*)(QT + (size_t)(x0 + r2) * 16384 + dc0 + y0 + xc) = h;
  }
}

// g-vector doubling, split: partial over 64-row strips, then reduce.
__global__ void gvec_part_k(const float* __restrict__ g, const float* __restrict__ R32,
                            float* __restrict__ gp) {
  const int j = blockIdx.x * 256 + threadIdx.x;
  const int i0 = blockIdx.y * 64;
  float s = 0.f;
#pragma unroll 4
  for (int i = 0; i < 64; ++i) s += g[i0 + i] * R32[(size_t)(i0 + i) * HID_ + j];
  gp[(size_t)blockIdx.y * HID_ + j] = s;
}
__global__ void gvec_red_k(const float* __restrict__ g, const float* __restrict__ gp,
                           float* __restrict__ gout) {
  const int j = blockIdx.x * 256 + threadIdx.x;
  float s = 0.f;
#pragma unroll
  for (int ib = 0; ib < 32; ++ib) s += gp[(size_t)ib * HID_ + j];
  gout[j] = 2.f * g[j] + s * (1.0f / 64.0f);
}

// ---------------------------------------------------------------- MFMA GEMM
// C = A(MxK) @ Bt(NxK)^T, fp16 16x16x32 MFMA, f32 acc. LDS unpadded, XOR
// chunk-swizzle: LDS[r][c] holds global chunk c^(r&7) (16B chunks).
// ASRC: 0=fp16 via global_load_lds, 1=f32 convert-stage
// BSRC: 0=fp16 via global_load_lds, 1=f32 convert-stage, N-bounded
// EPI : 0 squaring  R32/R16 <- acc/64 + 2*R32 (in-place-safe per element)
//       1 Qdouble   o16 = fp16(acc/64 + aux16)
//       2 inner     S[z] = 0.01*(acc + vecf[col]), A offset by z chunk
//       3 combine   PAIR: To[p] = acc/64 + Ti[2p] + Ti[2p+1]; else o32=acc/64+auxA+auxB
//       4 logits    o32 = (acc + vecf[col])/T, N-bounded
template<int BM, int BN, int BK, int WM, int WN, int ASRC, int BSRC, int EPI, int PAIR>
__global__ __launch_bounds__(256) void gemm_k(
    const void* __restrict__ Ap, int lda,
    const void* __restrict__ Bp, int ldb,
    int K, int Ntot, int ldc,
    float* __restrict__ o32, _Float16* __restrict__ o16,
    const float* __restrict__ auxA, const float* __restrict__ auxB,
    const _Float16* __restrict__ aux16,
    const float* __restrict__ vecf, const void* __restrict__ tptr) {
  __shared__ alignas(16) _Float16 At[BM][BK];
  __shared__ alignas(16) _Float16 Bts[BN][BK];
  constexpr int MF = WM / 16, NF = WN / 16, WNB = BN / WN;
  const int tid = threadIdx.x, lane = tid & 63, w = tid >> 6;
  const int wm0 = (w / WNB) * WM, wn0 = (w % WNB) * WN;
  const int bn0 = blockIdx.x * BN;
  const int bm0 = blockIdx.y * BM;
  const int pair = bm0 >> 7;          // used when PAIR
  const int rloc = bm0 & 127;

  size_t Aoff = 0;
  if constexpr (EPI == 2) Aoff = (size_t)blockIdx.z * 128 * 16384;

  f32x4 acc[MF][NF];
#pragma unroll
  for (int mf = 0; mf < MF; ++mf)
#pragma unroll
    for (int nf = 0; nf < NF; ++nf) acc[mf][nf] = (f32x4){0.f, 0.f, 0.f, 0.f};

  for (int k0 = 0; k0 < K; k0 += BK) {
    // ---- stage A
    if constexpr (ASRC == 0) {
      const _Float16* Ag = (const _Float16*)Ap + Aoff + (size_t)k0;
      const int abase = PAIR ? (pair * 256 + rloc) : bm0;
#pragma unroll
      for (int i = 0; i < BM / 32; ++i) {
        const int rowb = (i * 4 + w) * 8;
        const int row = rowb + (lane >> 3);
        const int cf = (lane & 7) ^ (row & 7);
        gl_lds16(Ag + (size_t)(abase + row) * lda + cf * 8, &At[rowb][0]);
      }
    } else {
      const float* Ag = (const float*)Ap;
      constexpr int CH = BK / 4;
#pragma unroll
      for (int c = 0; c < (BM * CH) / 256; ++c) {
        int t = tid + c * 256;
        int row = t / CH, kc = t % CH;
        int arow = PAIR ? (pair * 256 + rloc + row) : (bm0 + row);
        f32x4 v = *(const f32x4*)(Ag + (size_t)arow * lda + k0 + kc * 4);
        int col = (((kc >> 1) ^ (row & 7)) << 3) + ((kc & 1) << 2);
        *(half4h*)&At[row][col] =
            (half4h){ (_Float16)v[0], (_Float16)v[1], (_Float16)v[2], (_Float16)v[3] };
      }
    }
    // ---- stage Bt
    if constexpr (BSRC == 0) {
      const _Float16* Bg = (const _Float16*)Bp + (size_t)k0;
#pragma unroll
      for (int i = 0; i < BN / 32; ++i) {
        const int rowb = (i * 4 + w) * 8;
        const int row = rowb + (lane >> 3);
        const int cf = (lane & 7) ^ (row & 7);
        gl_lds16(Bg + (size_t)(bn0 + row) * ldb + cf * 8, &Bts[rowb][0]);
      }
    } else {
      const float* Bg = (const float*)Bp;
      constexpr int CH = BK / 4;
#pragma unroll
      for (int c = 0; c < (BN * CH) / 256; ++c) {
        int t = tid + c * 256;
        int row = t / CH, kc = t % CH;
        int gr = bn0 + row;
        half4h h = { (_Float16)0.f, (_Float16)0.f, (_Float16)0.f, (_Float16)0.f };
        if (gr < Ntot) {
          f32x4 v = *(const f32x4*)(Bg + (size_t)gr * ldb + k0 + kc * 4);
          h = (half4h){ (_Float16)v[0], (_Float16)v[1], (_Float16)v[2], (_Float16)v[3] };
        }
        int col = (((kc >> 1) ^ (row & 7)) << 3) + ((kc & 1) << 2);
        *(half4h*)&Bts[row][col] = h;
      }
    }
    __syncthreads();
#pragma unroll
    for (int kk = 0; kk < BK; kk += 32) {
      const int kb = kk + ((lane >> 4) << 3);
      half8 a[MF], b[NF];
#pragma unroll
      for (int mf = 0; mf < MF; ++mf) {
        const int row = wm0 + mf * 16 + (lane & 15);
        a[mf] = *(const half8*)&At[row][((kb >> 3) ^ (row & 7)) << 3];
      }
#pragma unroll
      for (int nf = 0; nf < NF; ++nf) {
        const int row = wn0 + nf * 16 + (lane & 15);
        b[nf] = *(const half8*)&Bts[row][((kb >> 3) ^ (row & 7)) << 3];
      }
#pragma unroll
      for (int mf = 0; mf < MF; ++mf)
#pragma unroll
        for (int nf = 0; nf < NF; ++nf)
          acc[mf][nf] = __builtin_amdgcn_mfma_f32_16x16x32_f16(a[mf], b[nf], acc[mf][nf], 0, 0, 0);
    }
    __syncthreads();
  }

  // ---- epilogue; C/D: col = lane&15, row = (lane>>4)*4 + reg
  float invT = 1.0f;
  if constexpr (EPI == 4) invT = 1.0f / decode_temp(tptr);
  constexpr size_t BS = (size_t)BATCH_ * HID_;
#pragma unroll
  for (int mf = 0; mf < MF; ++mf)
#pragma unroll
    for (int nf = 0; nf < NF; ++nf) {
      const int col = bn0 + wn0 + nf * 16 + (lane & 15);
      const int r0 = wm0 + mf * 16 + ((lane >> 4) << 2);
#pragma unroll
      for (int r = 0; r < 4; ++r) {
        const int row = r0 + r;
        const float x = acc[mf][nf][r];
        if constexpr (EPI == 0) {
          size_t idx = (size_t)(bm0 + row) * ldc + col;
          float val = x * (1.0f / 64.0f) + 2.0f * auxA[idx];
          o32[idx] = val;
          o16[idx] = (_Float16)val;
        } else if constexpr (EPI == 1) {
          size_t idx = (size_t)(bm0 + row) * ldc + col;
          o16[idx] = (_Float16)(x * (1.0f / 64.0f) + (float)aux16[idx]);
        } else if constexpr (EPI == 2) {
          size_t idx = (size_t)row * ldc + col;
          o32[(size_t)blockIdx.z * BS + idx] = 0.01f * (x + vecf[col]);
        } else if constexpr (EPI == 3) {
          if constexpr (PAIR) {
            size_t off = (size_t)(rloc + row) * ldc + col;
            o32[(size_t)pair * BS + off] =
                x * (1.0f / 64.0f) + auxA[(size_t)pair * 2 * BS + off]
                                   + auxA[((size_t)pair * 2 + 1) * BS + off];
          } else {
            size_t idx = (size_t)(bm0 + row) * ldc + col;
            o32[idx] = x * (1.0f / 64.0f) + auxA[idx] + auxB[idx];
          }
        } else {
          if (col < Ntot)
            o32[(size_t)(bm0 + row) * ldc + col] = (x + vecf[col]) * invT;
        }
      }
    }
}

// ---------------------------------------------------------------- softmax
__global__ void softmax_k(const float* __restrict__ lg, float* __restrict__ out) {
  const int row = blockIdx.x;
  const float* lr = lg + (size_t)row * VOC_;
  float* orow = out + (size_t)row * VOC_;
  __shared__ float red[8];
  const int tid = threadIdx.x, lane = tid & 63, wid = tid >> 6;
  float m = -1e30f;
  for (int i = tid; i < VOC_; i += 256) m = fmaxf(m, lr[i]);
  for (int off = 32; off > 0; off >>= 1) m = fmaxf(m, __shfl_down(m, off, 64));
  if (lane == 0) red[wid] = m;
  __syncthreads();
  if (tid == 0) {
    float mm = red[0];
    for (int i = 1; i < 4; ++i) mm = fmaxf(mm, red[i]);
    red[4] = mm;
  }
  __syncthreads();
  const float bmax = red[4];
  float s = 0.f;
  for (int i = tid; i < VOC_; i += 256) s += __expf(lr[i] - bmax);
  for (int off = 32; off > 0; off >>= 1) s += __shfl_down(s, off, 64);
  if (lane == 0) red[wid] = s;
  __syncthreads();
  if (tid == 0) red[5] = red[0] + red[1] + red[2] + red[3];
  __syncthreads();
  const float inv = 1.0f / red[5];
  for (int i = tid; i < VOC_; i += 256) orow[i] = __expf(lr[i] - bmax) * inv;
}

// ---------------------------------------------------------------- launcher
extern "C" void kernel_launch(void* const* d_in, const int* in_sizes, int n_in,
                              void* d_out, int out_size, void* d_ws, size_t ws_size,
                              hipStream_t stream) {
  const int*   ids  = (const int*)d_in[0];
  const float* h0   = (const float*)d_in[1];
  const float* embf = (const float*)d_in[2];
  const float* Win  = (const float*)d_in[3];
  const float* Wh   = (const float*)d_in[4];
  const float* bias = (const float*)d_in[5];
  const float* fcw  = (const float*)d_in[6];
  const float* fcb  = (const float*)d_in[7];
  const void*  temp = d_in[8];
  float* out = (float*)d_out;

  char* w = (char*)d_ws;
  size_t o = 0;
  auto alloc = [&](size_t bytes) { char* p = w + o; o += (bytes + 255) & ~(size_t)255; return p; };

  _Float16* Xg   = (_Float16*)alloc((size_t)SEQ_ * BATCH_ * EMB_ * 2);  // 134 MB
  float*    logits = (float*)Xg;   // alias: Xg dead before logits written
  float*    S    = (float*)alloc((size_t)32 * BATCH_ * HID_ * 4);
  float*    R32  = (float*)alloc((size_t)HID_ * HID_ * 4);
  _Float16* R16[2];
  R16[0] = (_Float16*)alloc((size_t)HID_ * HID_ * 2);
  R16[1] = (_Float16*)alloc((size_t)HID_ * HID_ * 2);
  _Float16* RTp[10];
  for (int i = 0; i < 10; ++i) RTp[i] = (_Float16*)alloc((size_t)HID_ * HID_ * 2);
  _Float16* Qst = (_Float16*)alloc((size_t)32 * EMB_ * HID_ * 2);
  _Float16* QT  = (_Float16*)alloc((size_t)HID_ * 16384 * 2);
  float* TA = (float*)alloc((size_t)16 * BATCH_ * HID_ * 4);
  float* TB = (float*)alloc((size_t)8 * BATCH_ * HID_ * 4);
  float* gp = (float*)alloc((size_t)32 * HID_ * 4);
  float* g[2];
  g[0] = (float*)alloc(HID_ * 4);
  g[1] = (float*)alloc(HID_ * 4);
  if (ws_size < o) return;  // needs ~450 MB scratch

  const size_t QSLOT = (size_t)EMB_ * HID_;

  gather_x_k<<<SEQ_ * BATCH_ / 4, 256, 0, stream>>>(ids, embf, Xg);
  prep_R_k<<<dim3(32, 32), 256, 0, stream>>>(Wh, R32, R16[0], RTp[0]);
  transpose_f2h_k<<<dim3(EMB_ / 64, HID_ / 64), 256, 0, stream>>>(Win, EMB_, Qst, HID_);
  copy_win_qt_k<<<(HID_ * EMB_ / 4) / 256, 256, 0, stream>>>(Win, QT);

  for (int j = 0; j < 5; ++j) {
    const int nb = 1 << j;
    // Q doubling: slots [nb,2nb) = slots [0,nb) @ P^(2^j)
    if (j < 3)
      gemm_k<64, 64, 64, 32, 32, 0, 0, 1, 0>
          <<<dim3(32, nb * 8), 256, 0, stream>>>(
          Qst, HID_, RTp[j], HID_, HID_, HID_, HID_,
          nullptr, Qst + (size_t)nb * QSLOT, nullptr, nullptr, Qst, nullptr, nullptr);
    else
      gemm_k<128, 128, 64, 64, 64, 0, 0, 1, 0>
          <<<dim3(16, nb * 4), 256, 0, stream>>>(
          Qst, HID_, RTp[j], HID_, HID_, HID_, HID_,
          nullptr, Qst + (size_t)nb * QSLOT, nullptr, nullptr, Qst, nullptr, nullptr);
    transpose_q_k<<<dim3(32, 8, nb), 256, 0, stream>>>(Qst, nb, QT);
    // g_{2m} = 2 g_m + (g_m @ R_m)/64
    const float* gin = (j == 0) ? bias : g[(j + 1) & 1];
    gvec_part_k<<<dim3(8, 32), 256, 0, stream>>>(gin, R32, gp);
    gvec_red_k<<<8, 256, 0, stream>>>(gin, gp, g[j & 1]);
    // squaring: R_{2m} = 2 R_m + R_m^2
    gemm_k<64, 64, 64, 32, 32, 0, 0, 0, 0>
        <<<dim3(32, 32), 256, 0, stream>>>(
        R16[j & 1], HID_, RTp[j], HID_, HID_, HID_, HID_,
        R32, R16[(j & 1) ^ 1], R32, nullptr, nullptr, nullptr, nullptr);
    transpose_f2h_k<<<dim3(32, 32), 256, 0, stream>>>(R32, HID_, RTp[j + 1], HID_);
  }
  // extra squarings: P^64..P^512 for the combine tree
  for (int j = 5; j < 9; ++j) {
    gemm_k<64, 64, 64, 32, 32, 0, 0, 0, 0>
        <<<dim3(32, 32), 256, 0, stream>>>(
        R16[j & 1], HID_, RTp[j], HID_, HID_, HID_, HID_,
        R32, R16[(j & 1) ^ 1], R32, nullptr, nullptr, nullptr, nullptr);
    transpose_f2h_k<<<dim3(32, 32), 256, 0, stream>>>(R32, HID_, RTp[j + 1], HID_);
  }

  // inner fused GEMM: S_q = 0.01*( X_q @ Qstack + beta ), K = 32*512
  gemm_k<128, 128, 64, 64, 64, 0, 0, 2, 0>
      <<<dim3(16, 1, 32), 256, 0, stream>>>(
      Xg, 16384, QT, 16384, 16384, HID_, HID_,
      S, nullptr, nullptr, nullptr, nullptr, g[0], nullptr);

  // fold h0: S_0 <- h0 @ P^32 + S_0
  gemm_k<64, 64, 64, 32, 32, 1, 0, 3, 0>
      <<<dim3(32, 2), 256, 0, stream>>>(
      h0, HID_, RTp[5], HID_, HID_, HID_, HID_,
      S, nullptr, h0, S, nullptr, nullptr, nullptr);

  // pair tree: T'[p] = T[2p] @ P^(32*2^(l-1)) + T[2p+1]
  const float* tin = S;
  float* tout = TA;
  int pairs = 16;
  for (int l = 1; l <= 5; ++l) {
    gemm_k<64, 64, 64, 32, 32, 1, 0, 3, 1>
        <<<dim3(32, pairs * 2), 256, 0, stream>>>(
        tin, HID_, RTp[4 + l], HID_, HID_, HID_, HID_,
        tout, nullptr, tin, nullptr, nullptr, nullptr, nullptr);
    tin = tout;
    tout = (tout == TA) ? TB : TA;
    pairs >>= 1;
  }
  const float* H = tin;  // = TA after 5 levels

  // logits = (H @ fc_w^T + fc_b)/T
  gemm_k<128, 128, 64, 64, 64, 1, 1, 4, 0>
      <<<dim3((VOC_ + 127) / 128, 1), 256, 0, stream>>>(
      H, HID_, fcw, HID_, HID_, VOC_, VOC_,
      logits, nullptr, nullptr, nullptr, nullptr, fcb, temp);

  softmax_k<<<BATCH_, 256, 0, stream>>>(logits, out);
}